// Round 7
// baseline (179.558 us; speedup 1.0000x reference)
//
#include <hip/hip_runtime.h>

#define GD(x,y) (((x)+(y)-1)/(y))

#define SH   10                // rows per bucket = 1024
#define BPR  (1 << SH)
#define G1   1024              // blocks in hist/fill passes
#define BS   256
#define BS2  1024              // spmmb block size

// P1: per-block bucket histogram (LDS), cnt layout bucket-major: cnt[b*G1 + blk]
__global__ void histb_k(const int* __restrict__ row, int* __restrict__ cnt,
                        int E, int NBK, int chunk){
    __shared__ int h[128];             // NBK <= 128 (N <= 131072 at SH=10)
    for (int i = threadIdx.x; i < NBK; i += BS) h[i] = 0;
    __syncthreads();
    int s = blockIdx.x * chunk, e = min(E, s + chunk);
    for (int i = s + threadIdx.x; i < e; i += BS)
        atomicAdd(&h[row[i] >> SH], 1);
    __syncthreads();
    for (int i = threadIdx.x; i < NBK; i += BS)
        cnt[(size_t)i * G1 + blockIdx.x] = h[i];
}

// ---- hierarchical exclusive scan over M ints ----
__global__ void scanA_k(const int* __restrict__ in, int* __restrict__ bsum, int M){
    __shared__ int lds[256];
    int t = threadIdx.x;
    int base = blockIdx.x * 1024 + t * 4;
    int s = 0;
    #pragma unroll
    for (int j = 0; j < 4; ++j) if (base + j < M) s += in[base + j];
    lds[t] = s; __syncthreads();
    for (int off = 128; off; off >>= 1){
        if (t < off) lds[t] += lds[t + off];
        __syncthreads();
    }
    if (t == 0) bsum[blockIdx.x] = lds[0];
}

// scanB + softmax(alpha) fused (both single-block-scale work)
__global__ void scanB_k(int* __restrict__ bsum, int NB,
                        const float* __restrict__ alpha, float* __restrict__ a, int na){
    __shared__ int lds[1024];
    int t = threadIdx.x;
    if (t == 0){
        float m = alpha[0];
        for (int i = 1; i < na; ++i) m = fmaxf(m, alpha[i]);
        float s = 0.f;
        for (int i = 0; i < na; ++i){ float e = expf(alpha[i] - m); a[i] = e; s += e; }
        float inv = 1.f / s;
        for (int i = 0; i < na; ++i) a[i] *= inv;
    }
    int v = (t < NB) ? bsum[t] : 0;
    lds[t] = v; __syncthreads();
    for (int off = 1; off < 1024; off <<= 1){
        int add = (t >= off) ? lds[t - off] : 0;
        __syncthreads();
        lds[t] += add;
        __syncthreads();
    }
    if (t < NB) bsum[t] = lds[t] - v;
}

__global__ void scanC_k(const int* __restrict__ in, const int* __restrict__ bsum,
                        int* __restrict__ outx, int M){
    __shared__ int lds[256];
    int t = threadIdx.x;
    int base = blockIdx.x * 1024 + t * 4;
    int d[4]; int s = 0;
    #pragma unroll
    for (int j = 0; j < 4; ++j){ d[j] = (base + j < M) ? in[base + j] : 0; s += d[j]; }
    lds[t] = s; __syncthreads();
    for (int off = 1; off < 256; off <<= 1){
        int add = (t >= off) ? lds[t - off] : 0;
        __syncthreads();
        lds[t] += add;
        __syncthreads();
    }
    int run = bsum[blockIdx.x] + lds[t] - s;
    #pragma unroll
    for (int j = 0; j < 4; ++j){
        int i = base + j;
        if (i < M){ outx[i] = run; run += d[j]; }
    }
}

// P3: scatter edges into bucket order via LDS cursors; pack {col | rloc<<17, val}
// 98 write streams per block -> active lines fit L2, no write amplification.
__global__ void fill3_k(const int* __restrict__ row, const int* __restrict__ col,
                        const float* __restrict__ val, const int* __restrict__ base,
                        int2* __restrict__ sep, int E, int NBK, int chunk){
    __shared__ int cur[128];
    for (int i = threadIdx.x; i < NBK; i += BS)
        cur[i] = base[(size_t)i * G1 + blockIdx.x];
    __syncthreads();
    int s = blockIdx.x * chunk, e = min(E, s + chunk);
    for (int i = s + threadIdx.x; i < e; i += BS){
        int r = row[i];
        int b = r >> SH;
        int pos = atomicAdd(&cur[b], 1);
        int2 pk;
        pk.x = col[i] | ((r & (BPR - 1)) << 17);
        pk.y = __float_as_int(val[i]);
        sep[pos] = pk;
    }
}

// y[n] = emb[idx[n]] @ W (128->2); out[n] = b + a0*y[n].
// Two rows per wave: lane = (row-half)*32 + sl, float4 per lane.
__global__ void proj_k(const float* __restrict__ emb, const int* __restrict__ idx,
                       const float* __restrict__ W, const float* __restrict__ b,
                       const float* __restrict__ a, float* __restrict__ y,
                       float* __restrict__ out, int N){
    int t = blockIdx.x * blockDim.x + threadIdx.x;
    int w = t >> 6;
    int lane = t & 63;
    int n = w * 2 + (lane >> 5);
    if (n >= N) return;
    int sl = lane & 31;
    float4 x = ((const float4*)(emb + (size_t)idx[n] * 128))[sl];
    int d0 = 4 * sl;
    float s0 = x.x * W[d0*2]   + x.y * W[d0*2+2] + x.z * W[d0*2+4] + x.w * W[d0*2+6];
    float s1 = x.x * W[d0*2+1] + x.y * W[d0*2+3] + x.z * W[d0*2+5] + x.w * W[d0*2+7];
    #pragma unroll
    for (int off = 16; off; off >>= 1){
        s0 += __shfl_down(s0, off, 32);
        s1 += __shfl_down(s1, off, 32);
    }
    if (sl == 0){
        float c = a[0];
        ((float2*)y)[n]   = make_float2(s0, s1);
        ((float2*)out)[n] = make_float2(b[0] + c * s0, b[1] + c * s1);
    }
}

// bucketed push SpMM: one block (1024 thr) per 1024-row bucket, plane-split
// LDS accumulator, exclusive row ownership -> no global atomics.
__global__ void spmmb_k(const int* __restrict__ bas, const int2* __restrict__ sep,
                        const float* __restrict__ y, float* __restrict__ nxt,
                        const float* __restrict__ a, int ai,
                        float* __restrict__ out, int N, int NBK, int E){
    __shared__ float accx[BPR];
    __shared__ float accy[BPR];
    int b = blockIdx.x;
    int t = threadIdx.x;
    accx[t] = 0.f; accy[t] = 0.f;
    __syncthreads();
    int s = bas[(size_t)b * G1];
    int e = (b + 1 < NBK) ? bas[(size_t)(b + 1) * G1] : E;
    int i = s + t;
    for (; i + 3 * BS2 < e; i += 4 * BS2){
        int2 p0 = sep[i], p1 = sep[i + BS2], p2 = sep[i + 2*BS2], p3 = sep[i + 3*BS2];
        float2 m0 = ((const float2*)y)[p0.x & 0x1FFFF];
        float2 m1 = ((const float2*)y)[p1.x & 0x1FFFF];
        float2 m2 = ((const float2*)y)[p2.x & 0x1FFFF];
        float2 m3 = ((const float2*)y)[p3.x & 0x1FFFF];
        float v0 = __int_as_float(p0.y), v1 = __int_as_float(p1.y);
        float v2 = __int_as_float(p2.y), v3 = __int_as_float(p3.y);
        atomicAdd(&accx[p0.x >> 17], v0 * m0.x); atomicAdd(&accy[p0.x >> 17], v0 * m0.y);
        atomicAdd(&accx[p1.x >> 17], v1 * m1.x); atomicAdd(&accy[p1.x >> 17], v1 * m1.y);
        atomicAdd(&accx[p2.x >> 17], v2 * m2.x); atomicAdd(&accy[p2.x >> 17], v2 * m2.y);
        atomicAdd(&accx[p3.x >> 17], v3 * m3.x); atomicAdd(&accy[p3.x >> 17], v3 * m3.y);
    }
    for (; i < e; i += BS2){
        int2 pk = sep[i];
        float v = __int_as_float(pk.y);
        float2 m = ((const float2*)y)[pk.x & 0x1FFFF];
        atomicAdd(&accx[pk.x >> 17], v * m.x);
        atomicAdd(&accy[pk.x >> 17], v * m.y);
    }
    __syncthreads();
    int n = (b << SH) + t;
    if (n < N){
        float2 z = make_float2(accx[t], accy[t]);
        ((float2*)nxt)[n] = z;
        float2 o = ((float2*)out)[n];
        o.x += a[ai] * z.x; o.y += a[ai] * z.y;
        ((float2*)out)[n] = o;
    }
}

extern "C" void kernel_launch(void* const* d_in, const int* in_sizes, int n_in,
                              void* d_out, int out_size, void* d_ws, size_t ws_size,
                              hipStream_t stream) {
    const int*   node_idx = (const int*)  d_in[0];
    const int*   adj_row  = (const int*)  d_in[1];
    const int*   adj_col  = (const int*)  d_in[2];
    const float* adj_val  = (const float*)d_in[3];
    const float* emb      = (const float*)d_in[4];
    const float* alpha    = (const float*)d_in[5];
    const float* W        = (const float*)d_in[6];
    const float* b        = (const float*)d_in[7];
    float* out = (float*)d_out;

    const int N = in_sizes[0];      // 100000
    const int E = in_sizes[1];      // 1600000
    const int L = in_sizes[5] - 1;  // 3
    const int NBK = GD(N, BPR);     // 98 buckets
    const int M = NBK * G1;         // flattened (bucket,block) counts
    const int NBA = GD(M, 1024);    // scan blocks for M (== NBK)
    const int chunk = GD(E, G1);

    // workspace
    char* w = (char*)d_ws;
    float* y    = (float*)w;  w += (size_t)N * 2 * 4;
    float* nxt  = (float*)w;  w += (size_t)N * 2 * 4;
    int2*  sep  = (int2*)w;   w += (size_t)E * 8;
    int*   cnt  = (int*)w;    w += (size_t)M * 4;
    int*   bas  = (int*)w;    w += (size_t)M * 4;
    int*   bsum = (int*)w;    w += 4096;
    float* a    = (float*)w;

    // one-time bucket counting sort of edges (no global atomics)
    histb_k<<<G1, BS, 0, stream>>>(adj_row, cnt, E, NBK, chunk);
    scanA_k<<<NBA, 256, 0, stream>>>(cnt, bsum, M);
    scanB_k<<<1, 1024, 0, stream>>>(bsum, NBA, alpha, a, L + 1);
    scanC_k<<<NBA, 256, 0, stream>>>(cnt, bsum, bas, M);
    fill3_k<<<G1, BS, 0, stream>>>(adj_row, adj_col, adj_val, bas, sep, E, NBK, chunk);

    // layer 0: project to 2 dims, init out
    proj_k<<<GD(N * 32, 256), 256, 0, stream>>>(emb, node_idx, W, b, a, y, out, N);

    // propagation layers: bucketed SpMM with fused out-accumulation
    for (int i = 0; i < L; ++i){
        spmmb_k<<<NBK, BS2, 0, stream>>>(bas, sep, y, nxt, a, i + 1, out, N, NBK, E);
        float* tmp = y; y = nxt; nxt = tmp;
    }
}